// Round 2
// baseline (1552.699 us; speedup 1.0000x reference)
//
#include <hip/hip_runtime.h>
#include <stdint.h>

#define Hn 512
#define Dn 128
#define Nn 64
#define Tn 512
#define NT (Nn*Tn)   // 32768

typedef unsigned int uint;
typedef unsigned short ushort;
typedef unsigned long long u64;

typedef __attribute__((ext_vector_type(4))) float f32x4;

// ---------- ws layout (bytes) ----------
// emitb : 0x0000000  NT*Hn*2  = 32 MB   (exp(emit-rowmax), bf16)
// rm    : 0x2000000  NT*4     = 128 KB
// wmat  : 0x2020000  Hn*Dn*4  = 256 KB
// bias  : 0x2060000  Hn*4     = 2 KB
// cs    : 0x2061000  Hn*4     (448/colmax of P)
// rcsg  : 0x2062000  Hn*4     (colmax/448)
// pq    : 0x2070000  16*32*64*8 = 256 KB (P fp8 e4m3, MFMA B-frag order [kt 0..15][nt 0..31][lane])

__device__ inline float bf2f(ushort u) { union { uint i; float f; } v; v.i = uint(u) << 16; return v.f; }
__device__ inline ushort f2bf(float f) {
  union { uint i; float f; } v; v.f = f;
  uint u = v.i;
  uint r = (u + 0x7FFFu + ((u >> 16) & 1u)) >> 16;
  return ushort(r);
}
// e4m3fn decode (non-negative only); used in finale only
__device__ inline float fp8val(uint b) {
  uint e = (b >> 3) & 15u, m = b & 7u;
  return e ? ldexpf((float)(8u + m), (int)e - 10) : ldexpf((float)m, -9);
}
// pack 8 floats (k-ascending) to 8 e4m3 bytes; SAME helper packs A and B frags,
// so any HW k-permutation within the 32-k tile cancels between operands.
__device__ inline u64 pack8fp8(const float* v, float qs) {
  int lo = 0, hi = 0;
  lo = __builtin_amdgcn_cvt_pk_fp8_f32(v[0] * qs, v[1] * qs, lo, false);
  lo = __builtin_amdgcn_cvt_pk_fp8_f32(v[2] * qs, v[3] * qs, lo, true);
  hi = __builtin_amdgcn_cvt_pk_fp8_f32(v[4] * qs, v[5] * qs, hi, false);
  hi = __builtin_amdgcn_cvt_pk_fp8_f32(v[6] * qs, v[7] * qs, hi, true);
  return (u64)(uint)lo | ((u64)(uint)hi << 32);
}

__global__ void k_prep(const float* __restrict__ py, float* __restrict__ wmat, float* __restrict__ bias) {
  int h = blockIdx.x, d = threadIdx.x;
  float p = py[h * Dn + d];
  float lp = logf(p), l1 = log1pf(-p);
  wmat[h * Dn + d] = lp - l1;
  float v = l1;
  for (int o = 1; o < 64; o <<= 1) v += __shfl_xor(v, o, 64);
  __shared__ float s2[2];
  if ((threadIdx.x & 63) == 0) s2[threadIdx.x >> 6] = v;
  __syncthreads();
  if (threadIdx.x == 0) bias[h] = s2[0] + s2[1];
}

// per-column max of P -> cs = 448/max, rcsg = max/448
__global__ void k_cs(const float* __restrict__ px, float* __restrict__ cs, float* __restrict__ rcsg) {
  int j = threadIdx.x;  // 512 threads
  float m = 0.f;
#pragma unroll 8
  for (int k = 0; k < Hn; k++) m = fmaxf(m, px[(size_t)k * Hn + j]);
  cs[j] = 448.0f / m;
  rcsg[j] = m * (1.0f / 448.0f);
}

// quantize P (col-scaled) into MFMA B-frag order: pq[(kt*32 + nt)*64 + lane] (8 bytes k-ascending)
__global__ __launch_bounds__(256) void k_pq(const float* __restrict__ px, const float* __restrict__ cs,
                                            u64* __restrict__ pq) {
  __shared__ float ksl[32][260];
  int g = blockIdx.x & 1, kt = blockIdx.x >> 1;  // kt = global k-tile 0..15
  int t = threadIdx.x;
  int k0 = kt * 32;
  for (int i = 0; i < 8; i++) {
    int q = i * 256 + t;          // float4 id over 32x64
    int row = q >> 6, c4 = q & 63;
    float4 v = *(const float4*)(px + (size_t)(k0 + row) * Hn + g * 256 + c4 * 4);
    ksl[row][c4 * 4 + 0] = v.x; ksl[row][c4 * 4 + 1] = v.y;
    ksl[row][c4 * 4 + 2] = v.z; ksl[row][c4 * 4 + 3] = v.w;
  }
  __syncthreads();
  for (int i = 0; i < 4; i++) {
    int fid = i * 256 + t;        // (ntl, lane)
    int ntl = fid >> 6, l = fid & 63;
    int col = ntl * 16 + (l & 15);
    int kr0 = (l >> 4) * 8;
    float csv = cs[g * 256 + col];
    float vv[8];
#pragma unroll
    for (int j = 0; j < 8; j++) vv[j] = ksl[kr0 + j][col];
    pq[(size_t)((kt * 32 + g * 16 + ntl) * 64 + l)] = pack8fp8(vv, csv);
  }
}

__global__ __launch_bounds__(256) void k_emit(const float* __restrict__ A, const float* __restrict__ wmat,
                                              const float* __restrict__ bias, ushort* __restrict__ eb) {
  __shared__ float As[Dn][64];
  __shared__ float Bs[Dn][64];
  int t = threadIdx.x;
  int r0 = blockIdx.y * 64, h0 = blockIdx.x * 64;
  int row = t >> 2, q = t & 3;
  for (int i = 0; i < 8; i++) {
    int ch = q + i * 4;
    float4 a = *(const float4*)(A + (size_t)(r0 + row) * Dn + ch * 4);
    As[ch * 4 + 0][row] = a.x; As[ch * 4 + 1][row] = a.y;
    As[ch * 4 + 2][row] = a.z; As[ch * 4 + 3][row] = a.w;
    float4 b = *(const float4*)(wmat + (size_t)(h0 + row) * Dn + ch * 4);
    Bs[ch * 4 + 0][row] = b.x; Bs[ch * 4 + 1][row] = b.y;
    Bs[ch * 4 + 2][row] = b.z; Bs[ch * 4 + 3][row] = b.w;
  }
  __syncthreads();
  int tx = t & 15, ty = t >> 4;
  float acc[4][4] = {};
  for (int k = 0; k < Dn; k++) {
    float av[4], bv[4];
    *(float4*)av = *(const float4*)&As[k][ty * 4];
    *(float4*)bv = *(const float4*)&Bs[k][tx * 4];
#pragma unroll
    for (int ii = 0; ii < 4; ii++)
#pragma unroll
      for (int jj = 0; jj < 4; jj++) acc[ii][jj] += av[ii] * bv[jj];
  }
  float bsv[4];
  *(float4*)bsv = *(const float4*)(bias + h0 + tx * 4);
#pragma unroll
  for (int ii = 0; ii < 4; ii++) {
    int r = r0 + ty * 4 + ii;
    ushort4 u;
    u.x = f2bf(acc[ii][0] + bsv[0]); u.y = f2bf(acc[ii][1] + bsv[1]);
    u.z = f2bf(acc[ii][2] + bsv[2]); u.w = f2bf(acc[ii][3] + bsv[3]);
    *(ushort4*)(eb + (size_t)r * Hn + h0 + tx * 4) = u;
  }
}

__global__ void k_rowmax(const ushort* __restrict__ eb, float* __restrict__ rm) {
  int r = blockIdx.x, lane = threadIdx.x;
  uint4 u = *(const uint4*)(eb + (size_t)r * Hn + lane * 8);
  float m = bf2f(ushort(u.x & 0xffff));
  m = fmaxf(m, bf2f(ushort(u.x >> 16)));
  m = fmaxf(m, bf2f(ushort(u.y & 0xffff))); m = fmaxf(m, bf2f(ushort(u.y >> 16)));
  m = fmaxf(m, bf2f(ushort(u.z & 0xffff))); m = fmaxf(m, bf2f(ushort(u.z >> 16)));
  m = fmaxf(m, bf2f(ushort(u.w & 0xffff))); m = fmaxf(m, bf2f(ushort(u.w >> 16)));
  for (int o = 1; o < 64; o <<= 1) m = fmaxf(m, __shfl_xor(m, o, 64));
  if (lane == 0) rm[r] = m;
}

__global__ void k_bexp(ushort* __restrict__ eb, const float* __restrict__ rm) {
  int i = blockIdx.x * 256 + threadIdx.x;
  uint* p = (uint*)eb;
  uint u = p[i];
  float m = rm[i >> 8];
  float f0 = expf(bf2f(ushort(u & 0xffff)) - m);
  float f1 = expf(bf2f(ushort(u >> 16)) - m);
  p[i] = uint(f2bf(f0)) | (uint(f2bf(f1)) << 16);
}

// 4 WGs x 1024 threads (16 waves, 4 waves/SIMD). Wave w owns n-tiles 2w,2w+1 (cols 32w..32w+31).
// P fp8 B-frags persist in registers (32 u64/lane). 2 barriers per step:
//   B0: AfL(quantized alpha frags) published -> MFMA reads
//   B2: per-seq wave-partial maxima published -> quantize (ut round-trip is WAVE-LOCAL)
__global__ __launch_bounds__(1024) void k_rec4(
    const ushort* __restrict__ eb, const float* __restrict__ rm,
    const u64* __restrict__ pq, const float* __restrict__ px,
    const float* __restrict__ rcsg, const int* __restrict__ lens,
    float* __restrict__ outp) {
  const int grp = blockIdx.x;        // 0..3
  const int t = threadIdx.x;         // 0..1023
  const int w = t >> 6;              // wave 0..15
  const int lane = t & 63, quad = (t >> 4) & 3, l15 = t & 15;

  __shared__ float ut[16][516];      // u values fp32 [seq][col]
  __shared__ u64 AfL[16 * 64];       // alpha A-frags [kt][lane]
  __shared__ float rcsL[512];
  __shared__ float sredM[16][20];    // per-seq per-wave partial max
  __shared__ float rqs0[16];
  __shared__ int lenl[16];

  // ---- persistent P fragments: wave w owns n-tiles 2w, 2w+1 ----
  u64 PR[32];
#pragma unroll
  for (int kt = 0; kt < 16; kt++)
#pragma unroll
    for (int i = 0; i < 2; i++)
      PR[kt * 2 + i] = pq[(size_t)((kt * 32 + w * 2 + i) * 64 + lane)];

  if (t < 512) rcsL[t] = rcsg[t];
  if (t < 16) lenl[t] = lens[grp * 16 + t];

  // lane-0-of-wave-w per-seq state (seq = w)
  float moW = 0.f, CaccW = 0.f, rmpre = 0.f;
  int lenw = 0;

  // ---- init: wave s computes u0[s][*] = px[0][j]*eb[s][0][j], full-row max ----
  {
    int s = w, c0 = lane * 8;
    const float* pxr = px + c0;
    const ushort* er = eb + (size_t)(grp * 16 + s) * Tn * Hn + c0;
    float4 p0 = *(const float4*)(pxr);
    float4 p1 = *(const float4*)(pxr + 4);
    float v[8];
    v[0] = p0.x * bf2f(er[0]); v[1] = p0.y * bf2f(er[1]);
    v[2] = p0.z * bf2f(er[2]); v[3] = p0.w * bf2f(er[3]);
    v[4] = p1.x * bf2f(er[4]); v[5] = p1.y * bf2f(er[5]);
    v[6] = p1.z * bf2f(er[6]); v[7] = p1.w * bf2f(er[7]);
#pragma unroll
    for (int j = 0; j < 8; j++) ut[s][c0 + j] = v[j];
    float m = 0.f;
#pragma unroll
    for (int j = 0; j < 8; j++) m = fmaxf(m, v[j]);
    for (int o = 1; o < 64; o <<= 1) m = fmaxf(m, __shfl_xor(m, o, 64));
    if (lane == 0) {
      rqs0[s] = 448.0f * __builtin_amdgcn_rcpf(m);
      moW = m * (1.0f / 448.0f);
      CaccW = rm[(size_t)(grp * 16 + w) * Tn];
      lenw = lens[grp * 16 + w];
      rmpre = rm[(size_t)(grp * 16 + w) * Tn + 1];
    }
  }
  __syncthreads();
  const int t_end = lenl[15];
  const int lenq = lenl[l15];

  // ---- step-0 quantize (one A-frag entry per thread: kt = w) ----
  u64 myfrag;
  {
    float qs = rqs0[l15];
    const int k0 = w * 32 + quad * 8;
    float vv[8];
#pragma unroll
    for (int j = 0; j < 8; j++) vv[j] = ut[l15][k0 + j];
    myfrag = pack8fp8(vv, qs);
    AfL[w * 64 + lane] = myfrag;
  }

  // ---- emit prefetch for ts=1 (4 seq rows x 2 cols per thread) ----
  const size_t seqstride = (size_t)Tn * Hn;
  const ushort* ep0 = eb + ((size_t)(grp * 16 + quad * 4) * Tn + 1) * Hn + w * 32 + l15;
  ushort bp0[4], bp1[4];
#pragma unroll
  for (int r = 0; r < 4; r++) {
    const ushort* e = ep0 + (size_t)r * seqstride;
    bp0[r] = e[0]; bp1[r] = e[16];
  }
  ep0 += Hn;  // -> row ts=2

  // ---- recursion: 2 barriers/step ----
  for (int ts = 1; ts < t_end; ts++) {
    __syncthreads();  // B0: AfL published
    // prefetch emit(ts+1) + rm(ts+1); drains at B2 (after MFMA phase)
    ushort bq0[4], bq1[4];
#pragma unroll
    for (int r = 0; r < 4; r++) {
      const ushort* e = ep0 + (size_t)r * seqstride;
      bq0[r] = e[0]; bq1[r] = e[16];
    }
    ep0 += Hn;
    float rmn = 0.f;
    if (lane == 0) rmn = rm[(size_t)(grp * 16 + w) * Tn + ts + 1];

    // MFMA: 16 k-tiles x 2 n-tiles, B from registers
    f32x4 ac0 = {0.f, 0.f, 0.f, 0.f}, ac1 = {0.f, 0.f, 0.f, 0.f};
#pragma unroll
    for (int kt = 0; kt < 16; kt++) {
      u64 af = AfL[kt * 64 + lane];
      ac0 = __builtin_amdgcn_mfma_f32_16x16x32_fp8_fp8((long)af, (long)PR[kt * 2 + 0], ac0, 0, 0, 0);
      ac1 = __builtin_amdgcn_mfma_f32_16x16x32_fp8_fp8((long)af, (long)PR[kt * 2 + 1], ac1, 0, 0, 0);
    }

    // epilogue: u = acc*rcs*emit (own 32-col window) + in-wave per-seq max
    const int jb = w * 32 + l15;
    const float rc0 = rcsL[jb], rc1 = rcsL[jb + 16];
    float mx0, mx1, mx2, mx3;
    {
      float u0 = ac0[0] * rc0 * bf2f(bp0[0]);
      float u1 = ac1[0] * rc1 * bf2f(bp1[0]);
      ut[quad * 4 + 0][jb] = u0; ut[quad * 4 + 0][jb + 16] = u1; mx0 = fmaxf(u0, u1);
      u0 = ac0[1] * rc0 * bf2f(bp0[1]);
      u1 = ac1[1] * rc1 * bf2f(bp1[1]);
      ut[quad * 4 + 1][jb] = u0; ut[quad * 4 + 1][jb + 16] = u1; mx1 = fmaxf(u0, u1);
      u0 = ac0[2] * rc0 * bf2f(bp0[2]);
      u1 = ac1[2] * rc1 * bf2f(bp1[2]);
      ut[quad * 4 + 2][jb] = u0; ut[quad * 4 + 2][jb + 16] = u1; mx2 = fmaxf(u0, u1);
      u0 = ac0[3] * rc0 * bf2f(bp0[3]);
      u1 = ac1[3] * rc1 * bf2f(bp1[3]);
      ut[quad * 4 + 3][jb] = u0; ut[quad * 4 + 3][jb + 16] = u1; mx3 = fmaxf(u0, u1);
    }
#pragma unroll
    for (int o = 1; o < 16; o <<= 1) {
      mx0 = fmaxf(mx0, __shfl_xor(mx0, o, 64));
      mx1 = fmaxf(mx1, __shfl_xor(mx1, o, 64));
      mx2 = fmaxf(mx2, __shfl_xor(mx2, o, 64));
      mx3 = fmaxf(mx3, __shfl_xor(mx3, o, 64));
    }
    if (l15 < 4) {
      float mv = (l15 == 0) ? mx0 : ((l15 == 1) ? mx1 : ((l15 == 2) ? mx2 : mx3));
      sredM[quad * 4 + l15][w] = mv;
    }
    __syncthreads();  // B2: sredM visible (ut round-trip is wave-local)

    // combine global max for seq l15; quantize own-window u (active seqs)
    if (ts < lenq) {
      float4 g0 = *(const float4*)&sredM[l15][0];
      float4 g1 = *(const float4*)&sredM[l15][4];
      float4 g2 = *(const float4*)&sredM[l15][8];
      float4 g3 = *(const float4*)&sredM[l15][12];
      float gm = fmaxf(
          fmaxf(fmaxf(fmaxf(g0.x, g0.y), fmaxf(g0.z, g0.w)),
                fmaxf(fmaxf(g1.x, g1.y), fmaxf(g1.z, g1.w))),
          fmaxf(fmaxf(fmaxf(g2.x, g2.y), fmaxf(g2.z, g2.w)),
                fmaxf(fmaxf(g3.x, g3.y), fmaxf(g3.z, g3.w))));
      float qs = 448.0f * __builtin_amdgcn_rcpf(gm);
      const int k0 = w * 32 + quad * 8;
      float vv[8];
#pragma unroll
      for (int j = 0; j < 8; j++) vv[j] = ut[l15][k0 + j];
      myfrag = pack8fp8(vv, qs);
      AfL[w * 64 + lane] = myfrag;
    }

    // per-seq log-normalizer (lane 0 of wave w handles seq w)
    if (lane == 0) {
      if (ts < lenw) {
        float4 g0 = *(const float4*)&sredM[w][0];
        float4 g1 = *(const float4*)&sredM[w][4];
        float4 g2 = *(const float4*)&sredM[w][8];
        float4 g3 = *(const float4*)&sredM[w][12];
        float gmw = fmaxf(
            fmaxf(fmaxf(fmaxf(g0.x, g0.y), fmaxf(g0.z, g0.w)),
                  fmaxf(fmaxf(g1.x, g1.y), fmaxf(g1.z, g1.w))),
            fmaxf(fmaxf(fmaxf(g2.x, g2.y), fmaxf(g2.z, g2.w)),
                  fmaxf(fmaxf(g3.x, g3.y), fmaxf(g3.z, g3.w))));
        CaccW += __logf(moW) + rmpre;
        moW = gmw * (1.0f / 448.0f);
      }
      rmpre = rmn;
    }
    // rotate prefetch
#pragma unroll
    for (int r = 0; r < 4; r++) { bp0[r] = bq0[r]; bp1[r] = bq1[r]; }
  }

  // ---- finale: sum dequantized final frags per seq ----
  __syncthreads();  // protect sredM reuse vs last quantize reads
  {
    float p = 0.f;
#pragma unroll
    for (int j = 0; j < 8; j++) p += fp8val((uint)(myfrag >> (8 * j)) & 0xffu);
    p += __shfl_xor(p, 16, 64);
    p += __shfl_xor(p, 32, 64);
    if (lane < 16) sredM[lane][w] = p;   // [seq][wave] partial sums over k-window
  }
  __syncthreads();
  if (lane == 0) {
    float S = 0.f;
#pragma unroll
    for (int ww = 0; ww < 16; ww++) S += sredM[w][ww];
    outp[grp * 16 + w] = CaccW + __logf(moW * S);
  }
}

extern "C" void kernel_launch(void* const* d_in, const int* in_sizes, int n_in,
                              void* d_out, int out_size, void* d_ws, size_t ws_size,
                              hipStream_t stream) {
  const float* seq = (const float*)d_in[0];
  const int* lens = (const int*)d_in[1];
  const float* px = (const float*)d_in[2];
  const float* py = (const float*)d_in[3];
  char* ws = (char*)d_ws;
  ushort* emitb = (ushort*)(ws + 0x0000000);
  float* rm     = (float*)(ws + 0x2000000);
  float* wmat   = (float*)(ws + 0x2020000);
  float* bias   = (float*)(ws + 0x2060000);
  float* cs     = (float*)(ws + 0x2061000);
  float* rcsg   = (float*)(ws + 0x2062000);
  u64* pq       = (u64*)(ws + 0x2070000);
  float* outp   = (float*)d_out;

  hipLaunchKernelGGL(k_prep, dim3(512), dim3(128), 0, stream, py, wmat, bias);
  hipLaunchKernelGGL(k_cs, dim3(1), dim3(512), 0, stream, px, cs, rcsg);
  hipLaunchKernelGGL(k_pq, dim3(32), dim3(256), 0, stream, px, cs, pq);
  hipLaunchKernelGGL(k_emit, dim3(8, 512), dim3(256), 0, stream, seq, wmat, bias, emitb);
  hipLaunchKernelGGL(k_rowmax, dim3(NT), dim3(64), 0, stream, emitb, rm);
  hipLaunchKernelGGL(k_bexp, dim3(NT), dim3(256), 0, stream, emitb, rm);
  hipLaunchKernelGGL(k_rec4, dim3(4), dim3(1024), 0, stream, emitb, rm, pq, px, rcsg, lens, outp);
}

// Round 3
// 1183.308 us; speedup vs baseline: 1.3122x; 1.3122x over previous
//
#include <hip/hip_runtime.h>
#include <stdint.h>

#define Hn 512
#define Dn 128
#define Nn 64
#define Tn 512
#define NT (Nn*Tn)   // 32768

typedef unsigned int uint;
typedef unsigned short ushort;
typedef unsigned long long u64;

typedef __attribute__((ext_vector_type(4))) float f32x4;

// ---------- ws layout (bytes) ----------
// emitb : 0x0000000  NT*Hn*2  = 32 MB   (exp(emit-rowmax), bf16; PERMUTED cols after k_bexp)
// rm    : 0x2000000  NT*4     = 128 KB
// wmat  : 0x2020000  Hn*Dn*4  = 256 KB
// bias  : 0x2060000  Hn*4     = 2 KB
// cs    : 0x2061000  Hn*4     (448/colmax of P)
// rcsg  : 0x2062000  Hn*4     (colmax/448)
// pq    : 0x2070000  16*32*64*8 = 256 KB (P fp8 e4m3, MFMA B-frag order [kt][nt][lane])

__device__ inline float bf2f(ushort u) { union { uint i; float f; } v; v.i = uint(u) << 16; return v.f; }
__device__ inline ushort f2bf(float f) {
  union { uint i; float f; } v; v.f = f;
  uint u = v.i;
  uint r = (u + 0x7FFFu + ((u >> 16) & 1u)) >> 16;
  return ushort(r);
}
// e4m3fn decode (non-negative only); finale only
__device__ inline float fp8val(uint b) {
  uint e = (b >> 3) & 15u, m = b & 7u;
  return e ? ldexpf((float)(8u + m), (int)e - 10) : ldexpf((float)m, -9);
}
// pack 8 floats (k-ascending) to 8 e4m3 bytes; SAME helper packs A and B frags,
// so any HW k-permutation within the 32-k tile cancels between operands.
__device__ inline u64 pack8fp8(const float* v, float qs) {
  int lo = 0, hi = 0;
  lo = __builtin_amdgcn_cvt_pk_fp8_f32(v[0] * qs, v[1] * qs, lo, false);
  lo = __builtin_amdgcn_cvt_pk_fp8_f32(v[2] * qs, v[3] * qs, lo, true);
  hi = __builtin_amdgcn_cvt_pk_fp8_f32(v[4] * qs, v[5] * qs, hi, false);
  hi = __builtin_amdgcn_cvt_pk_fp8_f32(v[6] * qs, v[7] * qs, hi, true);
  return (u64)(uint)lo | ((u64)(uint)hi << 32);
}

__global__ void k_prep(const float* __restrict__ py, float* __restrict__ wmat, float* __restrict__ bias) {
  int h = blockIdx.x, d = threadIdx.x;
  float p = py[h * Dn + d];
  float lp = logf(p), l1 = log1pf(-p);
  wmat[h * Dn + d] = lp - l1;
  float v = l1;
  for (int o = 1; o < 64; o <<= 1) v += __shfl_xor(v, o, 64);
  __shared__ float s2[2];
  if ((threadIdx.x & 63) == 0) s2[threadIdx.x >> 6] = v;
  __syncthreads();
  if (threadIdx.x == 0) bias[h] = s2[0] + s2[1];
}

__global__ void k_cs(const float* __restrict__ px, float* __restrict__ cs, float* __restrict__ rcsg) {
  int j = threadIdx.x;  // 512 threads
  float m = 0.f;
#pragma unroll 8
  for (int k = 0; k < Hn; k++) m = fmaxf(m, px[(size_t)k * Hn + j]);
  cs[j] = 448.0f / m;
  rcsg[j] = m * (1.0f / 448.0f);
}

// quantize P (col-scaled) into MFMA B-frag order: pq[(kt*32 + nt)*64 + lane]
__global__ __launch_bounds__(256) void k_pq(const float* __restrict__ px, const float* __restrict__ cs,
                                            u64* __restrict__ pq) {
  __shared__ float ksl[32][260];
  int g = blockIdx.x & 1, kt = blockIdx.x >> 1;
  int t = threadIdx.x;
  int k0 = kt * 32;
  for (int i = 0; i < 8; i++) {
    int q = i * 256 + t;
    int row = q >> 6, c4 = q & 63;
    float4 v = *(const float4*)(px + (size_t)(k0 + row) * Hn + g * 256 + c4 * 4);
    ksl[row][c4 * 4 + 0] = v.x; ksl[row][c4 * 4 + 1] = v.y;
    ksl[row][c4 * 4 + 2] = v.z; ksl[row][c4 * 4 + 3] = v.w;
  }
  __syncthreads();
  for (int i = 0; i < 4; i++) {
    int fid = i * 256 + t;
    int ntl = fid >> 6, l = fid & 63;
    int col = ntl * 16 + (l & 15);
    int kr0 = (l >> 4) * 8;
    float csv = cs[g * 256 + col];
    float vv[8];
#pragma unroll
    for (int j = 0; j < 8; j++) vv[j] = ksl[kr0 + j][col];
    pq[(size_t)((kt * 32 + g * 16 + ntl) * 64 + l)] = pack8fp8(vv, csv);
  }
}

__global__ __launch_bounds__(256) void k_emit(const float* __restrict__ A, const float* __restrict__ wmat,
                                              const float* __restrict__ bias, ushort* __restrict__ eb) {
  __shared__ float As[Dn][64];
  __shared__ float Bs[Dn][64];
  int t = threadIdx.x;
  int r0 = blockIdx.y * 64, h0 = blockIdx.x * 64;
  int row = t >> 2, q = t & 3;
  for (int i = 0; i < 8; i++) {
    int ch = q + i * 4;
    float4 a = *(const float4*)(A + (size_t)(r0 + row) * Dn + ch * 4);
    As[ch * 4 + 0][row] = a.x; As[ch * 4 + 1][row] = a.y;
    As[ch * 4 + 2][row] = a.z; As[ch * 4 + 3][row] = a.w;
    float4 b = *(const float4*)(wmat + (size_t)(h0 + row) * Dn + ch * 4);
    Bs[ch * 4 + 0][row] = b.x; Bs[ch * 4 + 1][row] = b.y;
    Bs[ch * 4 + 2][row] = b.z; Bs[ch * 4 + 3][row] = b.w;
  }
  __syncthreads();
  int tx = t & 15, ty = t >> 4;
  float acc[4][4] = {};
  for (int k = 0; k < Dn; k++) {
    float av[4], bv[4];
    *(float4*)av = *(const float4*)&As[k][ty * 4];
    *(float4*)bv = *(const float4*)&Bs[k][tx * 4];
#pragma unroll
    for (int ii = 0; ii < 4; ii++)
#pragma unroll
      for (int jj = 0; jj < 4; jj++) acc[ii][jj] += av[ii] * bv[jj];
  }
  float bsv[4];
  *(float4*)bsv = *(const float4*)(bias + h0 + tx * 4);
#pragma unroll
  for (int ii = 0; ii < 4; ii++) {
    int r = r0 + ty * 4 + ii;
    ushort4 u;
    u.x = f2bf(acc[ii][0] + bsv[0]); u.y = f2bf(acc[ii][1] + bsv[1]);
    u.z = f2bf(acc[ii][2] + bsv[2]); u.w = f2bf(acc[ii][3] + bsv[3]);
    *(ushort4*)(eb + (size_t)r * Hn + h0 + tx * 4) = u;
  }
}

__global__ void k_rowmax(const ushort* __restrict__ eb, float* __restrict__ rm) {
  int r = blockIdx.x, lane = threadIdx.x;
  uint4 u = *(const uint4*)(eb + (size_t)r * Hn + lane * 8);
  float m = bf2f(ushort(u.x & 0xffff));
  m = fmaxf(m, bf2f(ushort(u.x >> 16)));
  m = fmaxf(m, bf2f(ushort(u.y & 0xffff))); m = fmaxf(m, bf2f(ushort(u.y >> 16)));
  m = fmaxf(m, bf2f(ushort(u.z & 0xffff))); m = fmaxf(m, bf2f(ushort(u.z >> 16)));
  m = fmaxf(m, bf2f(ushort(u.w & 0xffff))); m = fmaxf(m, bf2f(ushort(u.w >> 16)));
  for (int o = 1; o < 64; o <<= 1) m = fmaxf(m, __shfl_xor(m, o, 64));
  if (lane == 0) rm[r] = m;
}

// exp(e - rm) AND permute cols within each row so k_rec can load 4 cols per seq
// with ONE b64: logical col c = w*64 + nt*16 + l15  ->  stored at w*64 + l15*4 + nt.
__global__ __launch_bounds__(256) void k_bexp(ushort* __restrict__ eb, const float* __restrict__ rm) {
  int row = blockIdx.x, tr = threadIdx.x;
  ushort* e = eb + (size_t)row * Hn;
  uint u = ((const uint*)e)[tr];
  float m = rm[row];
  ushort a = f2bf(expf(bf2f(ushort(u & 0xffff)) - m));
  ushort b = f2bf(expf(bf2f(ushort(u >> 16)) - m));
  __syncthreads();
  int c0 = 2 * tr, c1 = 2 * tr + 1;
  e[(c0 & ~63) + (c0 & 15) * 4 + ((c0 & 63) >> 4)] = a;
  e[(c1 & ~63) + (c1 & 15) * 4 + ((c1 & 63) >> 4)] = b;
}

// 4 WGs x 512 threads (8 waves, 2/SIMD). Wave w owns n-tiles 4w..4w+3 (cols 64w..64w+63).
// P fp8 B-frags persist in registers. TWO barriers per step:
//   B0: AfL (quantized alpha frags) published -> MFMA
//   B1: per-seq per-wave partial maxima (sredM) published -> quantize (ut round-trip is wave-local)
// All per-step scalar bookkeeping (rm, Cacc) evicted to the finale.
__global__ __launch_bounds__(512, 2) void k_rec5(
    const ushort* __restrict__ eb, const float* __restrict__ rm,
    const u64* __restrict__ pq, const float* __restrict__ px,
    const float* __restrict__ rcsg, const int* __restrict__ lens,
    float* __restrict__ outp) {
  const int grp = blockIdx.x;        // 0..3
  const int t = threadIdx.x;         // 0..511
  const int w = t >> 6;              // wave 0..7
  const int lane = t & 63, qg = lane >> 4, l15 = lane & 15;

  __shared__ float ut[16][516];      // u values fp32 [seq][col]
  __shared__ u64 AfL[16 * 64];       // alpha A-frags [kt][lane]
  __shared__ float sredM[16][12];    // per-seq per-wave partial max (row 48B -> f4-aligned)
  __shared__ float rmsL[16];
  __shared__ int lenl[16];

  // ---- persistent P fragments: wave w owns n-tiles 4w..4w+3 ----
  u64 PR[64];
#pragma unroll
  for (int kt = 0; kt < 16; kt++)
#pragma unroll
    for (int i = 0; i < 4; i++)
      PR[kt * 4 + i] = pq[(size_t)((kt * 32 + w * 4 + i) * 64 + lane)];

  // per-lane constants: dequant colscale for my 4 cols
  float rcv[4];
#pragma unroll
  for (int nt = 0; nt < 4; nt++) rcv[nt] = rcsg[w * 64 + nt * 16 + l15];

  if (t < 16) lenl[t] = lens[grp * 16 + t];

  const size_t seqstride = (size_t)Tn * Hn;

  // ---- init (t=0): u0 = px[0][c] * emit0[c]; same data placement as loop epilogue ----
  {
    float pxv[4];
#pragma unroll
    for (int nt = 0; nt < 4; nt++) pxv[nt] = px[w * 64 + nt * 16 + l15];
    float mx[4];
#pragma unroll
    for (int r = 0; r < 4; r++) {
      int s = qg * 4 + r;
      u64 ev = *(const u64*)(eb + (size_t)(grp * 16 + s) * seqstride + w * 64 + l15 * 4);
      float u0 = pxv[0] * bf2f(ushort(ev & 0xffff));
      float u1 = pxv[1] * bf2f(ushort((ev >> 16) & 0xffff));
      float u2 = pxv[2] * bf2f(ushort((ev >> 32) & 0xffff));
      float u3 = pxv[3] * bf2f(ushort(ev >> 48));
      ut[s][w * 64 + l15] = u0;
      ut[s][w * 64 + 16 + l15] = u1;
      ut[s][w * 64 + 32 + l15] = u2;
      ut[s][w * 64 + 48 + l15] = u3;
      mx[r] = fmaxf(fmaxf(u0, u1), fmaxf(u2, u3));
    }
#pragma unroll
    for (int o = 1; o < 16; o <<= 1) {
      mx[0] = fmaxf(mx[0], __shfl_xor(mx[0], o, 64));
      mx[1] = fmaxf(mx[1], __shfl_xor(mx[1], o, 64));
      mx[2] = fmaxf(mx[2], __shfl_xor(mx[2], o, 64));
      mx[3] = fmaxf(mx[3], __shfl_xor(mx[3], o, 64));
    }
    if (l15 == 0) {
#pragma unroll
      for (int r = 0; r < 4; r++) sredM[qg * 4 + r][w] = mx[r];
    }
  }
  __syncthreads();
  const int t_end = lenl[15];
  const int lenq = lenl[l15];
  float L2acc;
  u64 myf0, myf1;

  // ---- phase B0: combine gm (seq = l15), quantize step-0 frags (wave-local cols) ----
  {
    float4 g0 = *(const float4*)&sredM[l15][0];
    float4 g1 = *(const float4*)&sredM[l15][4];
    float gm = fmaxf(fmaxf(fmaxf(g0.x, g0.y), fmaxf(g0.z, g0.w)),
                     fmaxf(fmaxf(g1.x, g1.y), fmaxf(g1.z, g1.w)));
    L2acc = __log2f(gm);
    float qs = 448.0f * __builtin_amdgcn_rcpf(gm);
    float vv[8];
    float4 A = *(const float4*)&ut[l15][(2 * w) * 32 + qg * 8];
    float4 B = *(const float4*)&ut[l15][(2 * w) * 32 + qg * 8 + 4];
    vv[0] = A.x; vv[1] = A.y; vv[2] = A.z; vv[3] = A.w;
    vv[4] = B.x; vv[5] = B.y; vv[6] = B.z; vv[7] = B.w;
    myf0 = pack8fp8(vv, qs);
    AfL[(2 * w) * 64 + lane] = myf0;
    A = *(const float4*)&ut[l15][(2 * w + 1) * 32 + qg * 8];
    B = *(const float4*)&ut[l15][(2 * w + 1) * 32 + qg * 8 + 4];
    vv[0] = A.x; vv[1] = A.y; vv[2] = A.z; vv[3] = A.w;
    vv[4] = B.x; vv[5] = B.y; vv[6] = B.z; vv[7] = B.w;
    myf1 = pack8fp8(vv, qs);
    AfL[(2 * w + 1) * 64 + lane] = myf1;
  }

  // ---- emit prefetch pointers (4 seqs x b64 each), row ts=1 ----
  const ushort* ep[4];
#pragma unroll
  for (int r = 0; r < 4; r++)
    ep[r] = eb + ((size_t)(grp * 16 + qg * 4 + r) * Tn + 1) * Hn + w * 64 + l15 * 4;
  u64 bp[4];
#pragma unroll
  for (int r = 0; r < 4; r++) { bp[r] = *(const u64*)ep[r]; ep[r] += Hn; }

  // ---- recursion: 2 barriers/step ----
  for (int ts = 1; ts < t_end; ts++) {
    __syncthreads();  // B0: AfL published
    // prefetch emit(ts+1); consumed next iteration (drains at B1, long after issue)
    u64 bq[4];
#pragma unroll
    for (int r = 0; r < 4; r++) { bq[r] = *(const u64*)ep[r]; ep[r] += Hn; }

    // MFMA: 16 k-tiles x 4 n-tiles, B from registers
    f32x4 ac0 = {0.f, 0.f, 0.f, 0.f}, ac1 = {0.f, 0.f, 0.f, 0.f};
    f32x4 ac2 = {0.f, 0.f, 0.f, 0.f}, ac3 = {0.f, 0.f, 0.f, 0.f};
#pragma unroll
    for (int kt = 0; kt < 16; kt++) {
      u64 af = AfL[kt * 64 + lane];
      ac0 = __builtin_amdgcn_mfma_f32_16x16x32_fp8_fp8((long)af, (long)PR[kt * 4 + 0], ac0, 0, 0, 0);
      ac1 = __builtin_amdgcn_mfma_f32_16x16x32_fp8_fp8((long)af, (long)PR[kt * 4 + 1], ac1, 0, 0, 0);
      ac2 = __builtin_amdgcn_mfma_f32_16x16x32_fp8_fp8((long)af, (long)PR[kt * 4 + 2], ac2, 0, 0, 0);
      ac3 = __builtin_amdgcn_mfma_f32_16x16x32_fp8_fp8((long)af, (long)PR[kt * 4 + 3], ac3, 0, 0, 0);
    }

    // epilogue: u = acc*rcs*emit; per-seq wave-partial max folded in via shfl
    float mx[4];
    {
#pragma unroll
      for (int r = 0; r < 4; r++) {
        int s = qg * 4 + r;
        u64 ev = bp[r];
        float u0 = ac0[r] * rcv[0] * bf2f(ushort(ev & 0xffff));
        float u1 = ac1[r] * rcv[1] * bf2f(ushort((ev >> 16) & 0xffff));
        float u2 = ac2[r] * rcv[2] * bf2f(ushort((ev >> 32) & 0xffff));
        float u3 = ac3[r] * rcv[3] * bf2f(ushort(ev >> 48));
        ut[s][w * 64 + l15] = u0;
        ut[s][w * 64 + 16 + l15] = u1;
        ut[s][w * 64 + 32 + l15] = u2;
        ut[s][w * 64 + 48 + l15] = u3;
        mx[r] = fmaxf(fmaxf(u0, u1), fmaxf(u2, u3));
      }
#pragma unroll
      for (int o = 1; o < 16; o <<= 1) {
        mx[0] = fmaxf(mx[0], __shfl_xor(mx[0], o, 64));
        mx[1] = fmaxf(mx[1], __shfl_xor(mx[1], o, 64));
        mx[2] = fmaxf(mx[2], __shfl_xor(mx[2], o, 64));
        mx[3] = fmaxf(mx[3], __shfl_xor(mx[3], o, 64));
      }
      if (l15 == 0) {
#pragma unroll
        for (int r = 0; r < 4; r++) sredM[qg * 4 + r][w] = mx[r];
      }
    }
    __syncthreads();  // B1: sredM visible; ut round-trip is wave-local

    // phase B: per-lane seq = l15; combine gm, accumulate log2, quantize wave-local cols
    if (ts < lenq) {
      float4 g0 = *(const float4*)&sredM[l15][0];
      float4 g1 = *(const float4*)&sredM[l15][4];
      float gm = fmaxf(fmaxf(fmaxf(g0.x, g0.y), fmaxf(g0.z, g0.w)),
                       fmaxf(fmaxf(g1.x, g1.y), fmaxf(g1.z, g1.w)));
      L2acc += __log2f(gm);
      float qs = 448.0f * __builtin_amdgcn_rcpf(gm);
      float vv[8];
      float4 A = *(const float4*)&ut[l15][(2 * w) * 32 + qg * 8];
      float4 B = *(const float4*)&ut[l15][(2 * w) * 32 + qg * 8 + 4];
      vv[0] = A.x; vv[1] = A.y; vv[2] = A.z; vv[3] = A.w;
      vv[4] = B.x; vv[5] = B.y; vv[6] = B.z; vv[7] = B.w;
      myf0 = pack8fp8(vv, qs);
      AfL[(2 * w) * 64 + lane] = myf0;
      A = *(const float4*)&ut[l15][(2 * w + 1) * 32 + qg * 8];
      B = *(const float4*)&ut[l15][(2 * w + 1) * 32 + qg * 8 + 4];
      vv[0] = A.x; vv[1] = A.y; vv[2] = A.z; vv[3] = A.w;
      vv[4] = B.x; vv[5] = B.y; vv[6] = B.z; vv[7] = B.w;
      myf1 = pack8fp8(vv, qs);
      AfL[(2 * w + 1) * 64 + lane] = myf1;
    }
#pragma unroll
    for (int r = 0; r < 4; r++) bp[r] = bq[r];
  }

  // ---- finale ----
  __syncthreads();
  // S partials: my frags hold seq=l15, k-cols 64w..64w+63 (last active pack)
  {
    float ps = 0.f;
#pragma unroll
    for (int j = 0; j < 8; j++) {
      ps += fp8val((uint)(myf0 >> (8 * j)) & 0xffu);
      ps += fp8val((uint)(myf1 >> (8 * j)) & 0xffu);
    }
    ps += __shfl_xor(ps, 16, 64);
    ps += __shfl_xor(ps, 32, 64);
    if (lane < 16) sredM[lane][w] = ps;
  }
  // rm sums: wave w handles seqs 2w (lanes 0..31) and 2w+1 (lanes 32..63)
  {
    int sq = 2 * w + (lane >> 5), tl = lane & 31;
    const float* rp = rm + (size_t)(grp * 16 + sq) * Tn;
    int ls = lenl[sq];
    float rs = 0.f;
#pragma unroll
    for (int k = 0; k < 16; k++) {
      int idx = tl + 32 * k;
      float v = rp[idx];
      rs += (idx < ls) ? v : 0.f;
    }
#pragma unroll
    for (int o = 1; o < 32; o <<= 1) rs += __shfl_xor(rs, o, 64);
    if ((lane & 31) == 0) rmsL[sq] = rs;
  }
  __syncthreads();
  if (t < 16) {  // wave 0, lane t: holds L2acc for seq t
    float4 s0 = *(const float4*)&sredM[t][0];
    float4 s1 = *(const float4*)&sredM[t][4];
    float Ss = (s0.x + s0.y) + (s0.z + s0.w) + (s1.x + s1.y) + (s1.z + s1.w);
    outp[grp * 16 + t] = 0.6931471805599453f * L2acc - (float)lenq * 6.104793232414985f
                         + logf(Ss) + rmsL[t];
  }
}

extern "C" void kernel_launch(void* const* d_in, const int* in_sizes, int n_in,
                              void* d_out, int out_size, void* d_ws, size_t ws_size,
                              hipStream_t stream) {
  const float* seq = (const float*)d_in[0];
  const int* lens = (const int*)d_in[1];
  const float* px = (const float*)d_in[2];
  const float* py = (const float*)d_in[3];
  char* ws = (char*)d_ws;
  ushort* emitb = (ushort*)(ws + 0x0000000);
  float* rm     = (float*)(ws + 0x2000000);
  float* wmat   = (float*)(ws + 0x2020000);
  float* bias   = (float*)(ws + 0x2060000);
  float* cs     = (float*)(ws + 0x2061000);
  float* rcsg   = (float*)(ws + 0x2062000);
  u64* pq       = (u64*)(ws + 0x2070000);
  float* outp   = (float*)d_out;

  hipLaunchKernelGGL(k_prep, dim3(512), dim3(128), 0, stream, py, wmat, bias);
  hipLaunchKernelGGL(k_cs, dim3(1), dim3(512), 0, stream, px, cs, rcsg);
  hipLaunchKernelGGL(k_pq, dim3(32), dim3(256), 0, stream, px, cs, pq);
  hipLaunchKernelGGL(k_emit, dim3(8, 512), dim3(256), 0, stream, seq, wmat, bias, emitb);
  hipLaunchKernelGGL(k_rowmax, dim3(NT), dim3(64), 0, stream, emitb, rm);
  hipLaunchKernelGGL(k_bexp, dim3(NT), dim3(256), 0, stream, emitb, rm);
  hipLaunchKernelGGL(k_rec5, dim3(4), dim3(512), 0, stream, emitb, rm, pq, px, rcsg, lens, outp);
}